// Round 3
// baseline (361.642 us; speedup 1.0000x reference)
//
#include <hip/hip_runtime.h>
#include <math.h>

// Problem constants: B=32, O=4096, F=256, H=8, HID=128
#define MB_ 131072
#define F_  256
#define HID_ 128
#define H_  8
#define O_  4096
#define B_  32

typedef __attribute__((ext_vector_type(8))) short short8;
typedef __attribute__((ext_vector_type(4))) float f32x4;

static __device__ __forceinline__ unsigned short f2bf(float f) {
    unsigned int u = __float_as_uint(f);
    unsigned int r = (u + 0x7fffu + ((u >> 16) & 1u)) >> 16;  // RNE
    return (unsigned short)r;
}
static __device__ __forceinline__ float bflo(unsigned int u) {
    return __uint_as_float(u << 16);
}
static __device__ __forceinline__ float bfhi(unsigned int u) {
    return __uint_as_float(u & 0xffff0000u);
}
// order-preserving float->uint key for atomicMax
static __device__ __forceinline__ unsigned int fkey(float f) {
    unsigned int u = __float_as_uint(f);
    return (u & 0x80000000u) ? ~u : (u | 0x80000000u);
}

// pack 8 f32 (two float4) -> short8 bf16
static __device__ __forceinline__ short8 pack_bf16x8(const float4 a, const float4 b) {
    short8 r;
    r[0] = (short)f2bf(a.x); r[1] = (short)f2bf(a.y);
    r[2] = (short)f2bf(a.z); r[3] = (short)f2bf(a.w);
    r[4] = (short)f2bf(b.x); r[5] = (short)f2bf(b.y);
    r[6] = (short)f2bf(b.z); r[7] = (short)f2bf(b.w);
    return r;
}

// ---------------- Prep: transpose + bf16-cast weights, init Mmax ------------
__global__ __launch_bounds__(256) void k_prep(
    const float* __restrict__ W_in, const float* __restrict__ W_blk,
    unsigned short* __restrict__ WinT, unsigned short* __restrict__ WblkT,
    unsigned int* __restrict__ Mmax)
{
    const int idx = blockIdx.x * 256 + threadIdx.x;
    if (idx < 256) Mmax[idx] = 0u;  // key-space -inf
    if (idx < 32768) {
        const int n = idx >> 8, k = idx & 255;
        WinT[idx] = f2bf(W_in[(size_t)k * HID_ + n]);
    } else {
        const int i2 = idx - 32768;  // < 16384
        const int n = i2 >> 7, k = i2 & 127;
        WblkT[i2] = f2bf(W_blk[(size_t)k * HID_ + n]);
    }
}

// ---------------- Fused GEMM1+GEMM2, barrier-free GEMM1 ---------------------
// GEMM1: h = relu(x @ W_in + b_in). A-frags loaded DIRECTLY from x (f32,
// 32B/lane contiguous), B-frags directly from WinT (L2-hot). No LDS staging,
// no barriers in the K-loop: each wave pipelines independently (1-step reg
// prefetch), loads stay in flight ~90% of wave time -> HBM-bound.
// GEMM2: z = h @ W_blk. h tile via LDS (1 barrier), WblkT frags from L2.
__global__ __launch_bounds__(512, 4) void k_fused(
    const float* __restrict__ x, const unsigned short* __restrict__ WinT,
    const float* __restrict__ b_in,
    const unsigned short* __restrict__ WblkT, const float* __restrict__ b_blk,
    unsigned short* __restrict__ h_out, unsigned short* __restrict__ z_out,
    float* __restrict__ mask_out,
    float* __restrict__ sumP, float* __restrict__ sumsqP)
{
    __shared__ unsigned short h_s[128 * 136];   // 34816 B
    __shared__ float msum_s[128];
    __shared__ float csum_s[128], csumsq_s[128];

    const int tid = threadIdx.x;
    const int R0 = blockIdx.x * 128;
    const int wave = tid >> 6;   // 0..7
    const int wrow = wave >> 2;  // 0..1
    const int wcol = wave & 3;   // 0..3
    const int lane = tid & 63;
    const int lm = lane & 15, quad = lane >> 4;

    if (tid < 128) { msum_s[tid] = 0.f; csum_s[tid] = 0.f; csumsq_s[tid] = 0.f; }

    // per-wave base pointers
    const float* xr[4];
#pragma unroll
    for (int mi = 0; mi < 4; mi++)
        xr[mi] = x + (size_t)(R0 + wrow * 64 + mi * 16 + lm) * F_ + quad * 8;
    const unsigned short* wr[2];
#pragma unroll
    for (int ni = 0; ni < 2; ni++)
        wr[ni] = WinT + (size_t)(wcol * 32 + ni * 16 + lm) * F_ + quad * 8;

    f32x4 acc[4][2];
#pragma unroll
    for (int i = 0; i < 4; i++)
#pragma unroll
        for (int j = 0; j < 2; j++) acc[i][j] = (f32x4){0.f, 0.f, 0.f, 0.f};
    float ms[4] = {0.f, 0.f, 0.f, 0.f};

    // prologue: load step 0
    float4 aC[4][2];
    short8 bC[2];
#pragma unroll
    for (int mi = 0; mi < 4; mi++) {
        aC[mi][0] = *(const float4*)(xr[mi]);
        aC[mi][1] = *(const float4*)(xr[mi] + 4);
    }
#pragma unroll
    for (int ni = 0; ni < 2; ni++)
        bC[ni] = *(const short8*)(wr[ni]);

    __syncthreads();  // LDS sum-init visible before any later atomics

    // ---- GEMM1: 8 K-steps of 32, fully unrolled, no barriers ----
#pragma unroll
    for (int kt = 0; kt < 8; kt++) {
        float4 aN[4][2];
        short8 bN[2];
        if (kt < 7) {
#pragma unroll
            for (int mi = 0; mi < 4; mi++) {
                aN[mi][0] = *(const float4*)(xr[mi] + (kt + 1) * 32);
                aN[mi][1] = *(const float4*)(xr[mi] + (kt + 1) * 32 + 4);
            }
#pragma unroll
            for (int ni = 0; ni < 2; ni++)
                bN[ni] = *(const short8*)(wr[ni] + (kt + 1) * 32);
        }
        short8 af[4];
#pragma unroll
        for (int mi = 0; mi < 4; mi++) {
            const float4 u = aC[mi][0], v = aC[mi][1];
            if (wcol == 0)
                ms[mi] += u.x * u.x + u.y * u.y + u.z * u.z + u.w * u.w
                        + v.x * v.x + v.y * v.y + v.z * v.z + v.w * v.w;
            af[mi] = pack_bf16x8(u, v);
        }
#pragma unroll
        for (int mi = 0; mi < 4; mi++)
#pragma unroll
            for (int ni = 0; ni < 2; ni++)
                acc[mi][ni] = __builtin_amdgcn_mfma_f32_16x16x32_bf16(af[mi], bC[ni], acc[mi][ni], 0, 0, 0);
        if (kt < 7) {
#pragma unroll
            for (int mi = 0; mi < 4; mi++) { aC[mi][0] = aN[mi][0]; aC[mi][1] = aN[mi][1]; }
#pragma unroll
            for (int ni = 0; ni < 2; ni++) bC[ni] = bN[ni];
        }
    }

    // row-mask partials (4 quads per row jointly cover all 256 cols)
    if (wcol == 0) {
#pragma unroll
        for (int mi = 0; mi < 4; mi++)
            atomicAdd(&msum_s[wrow * 64 + mi * 16 + lm], ms[mi]);
    }

    // prefetch GEMM2 B fragments (WblkT, L2-hot) — overlap with epilogue 1
    short8 wb[4][2];
#pragma unroll
    for (int kt2 = 0; kt2 < 4; kt2++)
#pragma unroll
        for (int ni = 0; ni < 2; ni++)
            wb[kt2][ni] = *(const short8*)(WblkT + (size_t)(wcol * 32 + ni * 16 + lm) * HID_ + kt2 * 32 + quad * 8);

    // ---- epilogue 1: bias + relu, write h to global AND LDS h-tile ----
    {
        float bcol[2];
#pragma unroll
        for (int ni = 0; ni < 2; ni++) bcol[ni] = b_in[wcol * 32 + ni * 16 + lm];
#pragma unroll
        for (int mi = 0; mi < 4; mi++)
#pragma unroll
            for (int r = 0; r < 4; r++) {
                const int rl = wrow * 64 + mi * 16 + quad * 4 + r;
                const size_t grow = (size_t)(R0 + rl) * HID_;
#pragma unroll
                for (int ni = 0; ni < 2; ni++) {
                    const int col = wcol * 32 + ni * 16 + lm;
                    const float v = fmaxf(acc[mi][ni][r] + bcol[ni], 0.f);
                    const unsigned short us = f2bf(v);
                    h_out[grow + col] = us;
                    h_s[rl * 136 + col] = us;
                }
            }
    }
#pragma unroll
    for (int i = 0; i < 4; i++)
#pragma unroll
        for (int j = 0; j < 2; j++) acc[i][j] = (f32x4){0.f, 0.f, 0.f, 0.f};
    __syncthreads();   // h_s complete, msum complete

    if (tid < 128) mask_out[R0 + tid] = (msum_s[tid] != 0.f) ? 1.f : 0.f;

    // ---- GEMM2: A from h_s (LDS), B from registers ----
#pragma unroll
    for (int kt2 = 0; kt2 < 4; kt2++) {
        short8 haf[4];
#pragma unroll
        for (int mi = 0; mi < 4; mi++)
            haf[mi] = *(const short8*)(&h_s[(wrow * 64 + mi * 16 + lm) * 136 + kt2 * 32 + quad * 8]);
#pragma unroll
        for (int mi = 0; mi < 4; mi++)
#pragma unroll
            for (int ni = 0; ni < 2; ni++)
                acc[mi][ni] = __builtin_amdgcn_mfma_f32_16x16x32_bf16(haf[mi], wb[kt2][ni], acc[mi][ni], 0, 0, 0);
    }

    // ---- epilogue 2: bias, BN partials, z store ----
    float bcol2[2];
#pragma unroll
    for (int ni = 0; ni < 2; ni++) bcol2[ni] = b_blk[wcol * 32 + ni * 16 + lm];
    float s_c[2] = {0.f, 0.f}, ss_c[2] = {0.f, 0.f};
#pragma unroll
    for (int mi = 0; mi < 4; mi++)
#pragma unroll
        for (int r = 0; r < 4; r++) {
            const size_t row = (size_t)R0 + wrow * 64 + mi * 16 + quad * 4 + r;
#pragma unroll
            for (int ni = 0; ni < 2; ni++) {
                const float zv = acc[mi][ni][r] + bcol2[ni];
                s_c[ni] += zv;
                ss_c[ni] += zv * zv;
                z_out[row * HID_ + wcol * 32 + ni * 16 + lm] = f2bf(zv);
            }
        }
#pragma unroll
    for (int ni = 0; ni < 2; ni++) {
        atomicAdd(&csum_s[wcol * 32 + ni * 16 + lm], s_c[ni]);
        atomicAdd(&csumsq_s[wcol * 32 + ni * 16 + lm], ss_c[ni]);
    }
    __syncthreads();
    if (tid < 128) {
        sumP[(size_t)blockIdx.x * 128 + tid] = csum_s[tid];
        sumsqP[(size_t)blockIdx.x * 128 + tid] = csumsq_s[tid];
    }
}

// ---------------- BN finalize ----------------------------------------------
__global__ __launch_bounds__(256) void k_bnfin(
    const float* __restrict__ sumP, const float* __restrict__ sumsqP,
    const float* __restrict__ gamma, const float* __restrict__ beta,
    float* __restrict__ scale, float* __restrict__ shift)
{
    const int c = blockIdx.x;
    const int tid = threadIdx.x;
    float s = 0.f, ss = 0.f;
    for (int i = tid; i < 1024; i += 256) {
        s  += sumP[(size_t)i * 128 + c];
        ss += sumsqP[(size_t)i * 128 + c];
    }
#pragma unroll
    for (int off = 32; off; off >>= 1) {
        s  += __shfl_xor(s, off, 64);
        ss += __shfl_xor(ss, off, 64);
    }
    __shared__ float rs[4], rss[4];
    const int wid = tid >> 6, lane = tid & 63;
    if (lane == 0) { rs[wid] = s; rss[wid] = ss; }
    __syncthreads();
    if (tid == 0) {
        const float S  = rs[0] + rs[1] + rs[2] + rs[3];
        const float SS = rss[0] + rss[1] + rss[2] + rss[3];
        const float inv_m = 1.0f / (float)MB_;
        const float mu = S * inv_m;
        const float var = SS * inv_m - mu * mu;
        const float sc = gamma[c] * rsqrtf(var + 1e-5f);
        scale[c] = sc;
        shift[c] = beta[c] - mu * sc;
    }
}

// ---------------- logits + gumbel + per-(b,h) max ---------------------------
__global__ __launch_bounds__(256) void k_logits(
    const unsigned short* __restrict__ h_in, const unsigned short* __restrict__ z_in,
    const float* __restrict__ scale, const float* __restrict__ shift,
    const float* __restrict__ W_fc, const float* __restrict__ b_fc,
    const float* __restrict__ mask, const float* __restrict__ gumbel,
    float* __restrict__ t_out, unsigned int* __restrict__ Mmax)
{
    __shared__ float wfc_s[1024];
    __shared__ float sc_s[128], sh_s[128];
    const int tid = threadIdx.x;
    for (int i = tid; i < 1024; i += 256) wfc_s[i] = W_fc[i];
    if (tid < 128) { sc_s[tid] = scale[tid]; sh_s[tid] = shift[tid]; }
    __syncthreads();

    const size_t row0 = (size_t)blockIdx.x * 512 + tid;
    const size_t row1 = row0 + 256;
    float a0[8], a1[8];
#pragma unroll
    for (int j = 0; j < 8; j++) { a0[j] = 0.f; a1[j] = 0.f; }

    const uint4* hp0 = (const uint4*)(h_in + row0 * HID_);
    const uint4* zq0 = (const uint4*)(z_in + row0 * HID_);
    const uint4* hp1 = (const uint4*)(h_in + row1 * HID_);
    const uint4* zq1 = (const uint4*)(z_in + row1 * HID_);

#pragma unroll 2
    for (int kc = 0; kc < 16; kc++) {
        const uint4 h0 = hp0[kc], z0 = zq0[kc];
        const uint4 h1 = hp1[kc], z1 = zq1[kc];
        const unsigned int hs0[4] = {h0.x, h0.y, h0.z, h0.w};
        const unsigned int zs0[4] = {z0.x, z0.y, z0.z, z0.w};
        const unsigned int hs1[4] = {h1.x, h1.y, h1.z, h1.w};
        const unsigned int zs1[4] = {z1.x, z1.y, z1.z, z1.w};
#pragma unroll
        for (int p = 0; p < 4; p++) {
            const int k = kc * 8 + p * 2;
            const float sck0 = sc_s[k], shk0 = sh_s[k];
            const float sck1 = sc_s[k + 1], shk1 = sh_s[k + 1];
            const float4 wA = *(const float4*)&wfc_s[k * 8];
            const float4 wB = *(const float4*)&wfc_s[k * 8 + 4];
            const float4 wC = *(const float4*)&wfc_s[k * 8 + 8];
            const float4 wD = *(const float4*)&wfc_s[k * 8 + 12];
            {
                const float hf0 = bflo(hs0[p]), hf1 = bfhi(hs0[p]);
                const float zf0 = bflo(zs0[p]), zf1 = bfhi(zs0[p]);
                const float hb0 = fmaxf(zf0 * sck0 + shk0, 0.f) + hf0;
                const float hb1 = fmaxf(zf1 * sck1 + shk1, 0.f) + hf1;
                a0[0] += hb0 * wA.x + hb1 * wC.x;  a0[1] += hb0 * wA.y + hb1 * wC.y;
                a0[2] += hb0 * wA.z + hb1 * wC.z;  a0[3] += hb0 * wA.w + hb1 * wC.w;
                a0[4] += hb0 * wB.x + hb1 * wD.x;  a0[5] += hb0 * wB.y + hb1 * wD.y;
                a0[6] += hb0 * wB.z + hb1 * wD.z;  a0[7] += hb0 * wB.w + hb1 * wD.w;
            }
            {
                const float hf0 = bflo(hs1[p]), hf1 = bfhi(hs1[p]);
                const float zf0 = bflo(zs1[p]), zf1 = bfhi(zs1[p]);
                const float hb0 = fmaxf(zf0 * sck0 + shk0, 0.f) + hf0;
                const float hb1 = fmaxf(zf1 * sck1 + shk1, 0.f) + hf1;
                a1[0] += hb0 * wA.x + hb1 * wC.x;  a1[1] += hb0 * wA.y + hb1 * wC.y;
                a1[2] += hb0 * wA.z + hb1 * wC.z;  a1[3] += hb0 * wA.w + hb1 * wC.w;
                a1[4] += hb0 * wB.x + hb1 * wD.x;  a1[5] += hb0 * wB.y + hb1 * wD.y;
                a1[6] += hb0 * wB.z + hb1 * wD.z;  a1[7] += hb0 * wB.w + hb1 * wD.w;
            }
        }
    }

    float bf[8];
#pragma unroll
    for (int j = 0; j < 8; j++) bf[j] = b_fc[j];
    const float mk0 = mask[row0], mk1 = mask[row1];
    float g0[8], g1[8];
    *(float4*)&g0[0] = *(const float4*)(gumbel + row0 * 8);
    *(float4*)&g0[4] = *(const float4*)(gumbel + row0 * 8 + 4);
    *(float4*)&g1[0] = *(const float4*)(gumbel + row1 * 8);
    *(float4*)&g1[4] = *(const float4*)(gumbel + row1 * 8 + 4);
    float t0[8], t1[8];
#pragma unroll
    for (int j = 0; j < 8; j++) {
        t0[j] = (a0[j] + bf[j]) * mk0 + g0[j];
        t1[j] = (a1[j] + bf[j]) * mk1 + g1[j];
    }
    *(float4*)(t_out + row0 * 8)     = *(float4*)&t0[0];
    *(float4*)(t_out + row0 * 8 + 4) = *(float4*)&t0[4];
    *(float4*)(t_out + row1 * 8)     = *(float4*)&t1[0];
    *(float4*)(t_out + row1 * 8 + 4) = *(float4*)&t1[4];

    float tm[8];
#pragma unroll
    for (int j = 0; j < 8; j++) tm[j] = fmaxf(t0[j], t1[j]);
#pragma unroll
    for (int off = 32; off; off >>= 1)
#pragma unroll
        for (int j = 0; j < 8; j++) tm[j] = fmaxf(tm[j], __shfl_xor(tm[j], off, 64));
    if ((tid & 63) == 0) {
        const int bb = blockIdx.x >> 3;   // 512 rows per block, 4096 per b
#pragma unroll
        for (int j = 0; j < 8; j++) atomicMax(&Mmax[bb * 8 + j], fkey(tm[j]));
    }
}

// ---------------- pool: e=exp(t-M) on the fly, unnormalized wsum + Z --------
__global__ __launch_bounds__(256) void k_pool(
    const float* __restrict__ x, const float* __restrict__ t_in,
    const unsigned int* __restrict__ Mmax,
    float* __restrict__ pp, float* __restrict__ zp)
{
    __shared__ float ws_s[8][64];
    __shared__ float M_s[8];
    const int tid = threadIdx.x;
    const int oc = blockIdx.x;
    const int b  = blockIdx.y;
    if (tid < 8) {
        const unsigned int k = Mmax[b * 8 + tid];
        const unsigned int s = (k & 0x80000000u) ? (k & 0x7fffffffu) : ~k;
        M_s[tid] = __uint_as_float(s);
    }
    __syncthreads();
#pragma unroll
    for (int i = tid; i < 512; i += 256) {
        const int ol = i >> 3, hh = i & 7;
        const float tv = t_in[((size_t)b * O_ + oc * 64 + ol) * H_ + hh];
        ws_s[hh][ol] = __expf(tv - M_s[hh]);
    }
    __syncthreads();
    if (tid < 8) {
        float s = 0.f;
        for (int o = 0; o < 64; o++) s += ws_s[tid][o];
        zp[((size_t)oc * 32 + b) * 8 + tid] = s;
    }
    float acc[8];
#pragma unroll
    for (int hh = 0; hh < 8; hh++) acc[hh] = 0.f;
    const float* xp = x + ((size_t)b * O_ + oc * 64) * F_ + tid;
#pragma unroll 4
    for (int o = 0; o < 64; o++) {
        const float xv = xp[(size_t)o * F_];
#pragma unroll
        for (int hh = 0; hh < 8; hh++) acc[hh] += ws_s[hh][o] * xv;
    }
    float* outp = pp + ((size_t)oc * 32 + b) * 2048;
#pragma unroll
    for (int hh = 0; hh < 8; hh++) outp[hh * 256 + tid] = acc[hh];
}

// ---------------- reduce partials + divide by Z -----------------------------
__global__ __launch_bounds__(256) void k_reduce(
    const float* __restrict__ pp, const float* __restrict__ zp,
    float* __restrict__ out)
{
    const int blk = blockIdx.x;
    const int b = blk >> 3, hh = blk & 7;
    const int tid = threadIdx.x;
    __shared__ float invZ_s;
    if (tid < 64) {
        float z = zp[((size_t)tid * 32 + b) * 8 + hh];
#pragma unroll
        for (int off = 32; off; off >>= 1) z += __shfl_xor(z, off, 64);
        if (tid == 0) invZ_s = 1.f / z;
    }
    __syncthreads();
    float s = 0.f;
    const float* p0 = pp + (size_t)b * 2048 + hh * 256 + tid;
#pragma unroll 8
    for (int ocq = 0; ocq < 64; ocq++) s += p0[(size_t)ocq * 65536];
    out[(size_t)b * 2048 + hh * 256 + tid] = s * invZ_s;
}

extern "C" void kernel_launch(void* const* d_in, const int* in_sizes, int n_in,
                              void* d_out, int out_size, void* d_ws, size_t ws_size,
                              hipStream_t stream)
{
    const float* x      = (const float*)d_in[0];
    const float* gumbel = (const float*)d_in[1];
    const float* W_in   = (const float*)d_in[2];
    const float* b_in   = (const float*)d_in[3];
    const float* W_blk  = (const float*)d_in[4];
    const float* b_blk  = (const float*)d_in[5];
    const float* gamma  = (const float*)d_in[6];
    const float* beta   = (const float*)d_in[7];
    const float* W_fc   = (const float*)d_in[8];
    const float* b_fc   = (const float*)d_in[9];
    float* out = (float*)d_out;
    char* ws = (char*)d_ws;

    unsigned short* h_bf  = (unsigned short*)(ws + 0);            // 33554432
    float* pp     = (float*)(ws + 0);                              // 16777216 (alias)
    float* zp     = (float*)(ws + 16777216);                       // 65536    (alias)
    unsigned short* z_bf  = (unsigned short*)(ws + 33554432);      // 33554432
    float* mask   = (float*)(ws + 67108864);                       // 524288
    float* sumP   = (float*)(ws + 67633152);                       // 524288
    float* sumsqP = (float*)(ws + 68157440);                       // 524288
    float* scale  = (float*)(ws + 68681728);                       // 512
    float* shift  = (float*)(ws + 68682240);                       // 512
    float* t_buf  = (float*)(ws + 68682752);                       // 4194304
    unsigned int* Mmax = (unsigned int*)(ws + 72877056);           // 1024
    unsigned short* WinT  = (unsigned short*)(ws + 72878080);      // 65536
    unsigned short* WblkT = (unsigned short*)(ws + 72943616);      // 32768

    k_prep<<<192, 256, 0, stream>>>(W_in, W_blk, WinT, WblkT, Mmax);
    k_fused<<<1024, 512, 0, stream>>>(x, WinT, b_in, WblkT, b_blk, h_bf, z_bf, mask, sumP, sumsqP);
    k_bnfin<<<128, 256, 0, stream>>>(sumP, sumsqP, gamma, beta, scale, shift);
    k_logits<<<256, 256, 0, stream>>>(h_bf, z_bf, scale, shift, W_fc, b_fc, mask, gumbel, t_buf, Mmax);
    k_pool<<<dim3(64, 32), 256, 0, stream>>>(x, t_buf, Mmax, pp, zp);
    k_reduce<<<256, 256, 0, stream>>>(pp, zp, out);
}

// Round 5
// 303.868 us; speedup vs baseline: 1.1901x; 1.1901x over previous
//
#include <hip/hip_runtime.h>
#include <math.h>

// Problem constants: B=32, O=4096, F=256, H=8, HID=128
#define MB_ 131072
#define F_  256
#define HID_ 128
#define H_  8
#define O_  4096
#define B_  32

typedef __attribute__((ext_vector_type(8))) short short8;
typedef __attribute__((ext_vector_type(4))) float f32x4;

static __device__ __forceinline__ unsigned short f2bf(float f) {
    unsigned int u = __float_as_uint(f);
    unsigned int r = (u + 0x7fffu + ((u >> 16) & 1u)) >> 16;  // RNE
    return (unsigned short)r;
}
static __device__ __forceinline__ float bflo(unsigned int u) {
    return __uint_as_float(u << 16);
}
static __device__ __forceinline__ float bfhi(unsigned int u) {
    return __uint_as_float(u & 0xffff0000u);
}
// order-preserving float->uint key for atomicMax
static __device__ __forceinline__ unsigned int fkey(float f) {
    unsigned int u = __float_as_uint(f);
    return (u & 0x80000000u) ? ~u : (u | 0x80000000u);
}
// pack 8 f32 (two float4) -> short8 bf16
static __device__ __forceinline__ short8 pack_bf16x8(const float4 a, const float4 b) {
    short8 r;
    r[0] = (short)f2bf(a.x); r[1] = (short)f2bf(a.y);
    r[2] = (short)f2bf(a.z); r[3] = (short)f2bf(a.w);
    r[4] = (short)f2bf(b.x); r[5] = (short)f2bf(b.y);
    r[6] = (short)f2bf(b.z); r[7] = (short)f2bf(b.w);
    return r;
}
// raw barrier: waits only LDS ops of this wave, does NOT drain vmcnt
// (so in-flight global prefetch survives the barrier)
static __device__ __forceinline__ void sync_lds() {
    asm volatile("s_waitcnt lgkmcnt(0)" ::: "memory");
    __builtin_amdgcn_s_barrier();
    __builtin_amdgcn_sched_barrier(0);
}

// ---------------- Prep: transpose + bf16-cast weights, init Mmax ------------
__global__ __launch_bounds__(256) void k_prep(
    const float* __restrict__ W_in, const float* __restrict__ W_blk,
    unsigned short* __restrict__ WinT, unsigned short* __restrict__ WblkT,
    unsigned int* __restrict__ Mmax)
{
    const int idx = blockIdx.x * 256 + threadIdx.x;
    if (idx < 256) Mmax[idx] = 0u;  // key-space -inf
    if (idx < 32768) {
        const int n = idx >> 8, k = idx & 255;
        WinT[idx] = f2bf(W_in[(size_t)k * HID_ + n]);
    } else {
        const int i2 = idx - 32768;  // < 16384
        const int n = i2 >> 7, k = i2 & 127;
        WblkT[i2] = f2bf(W_blk[(size_t)k * HID_ + n]);
    }
}

// ---------------- Fused GEMM1+GEMM2 -----------------------------------------
// LDS = 32768 B exactly: stg[2][128][32] bf16 (16 KB, swizzled) unioned with
// h_s[128][128] bf16 (32 KB, XOR-swizzled, stride 128).
// K-loop uses raw s_barrier + lgkmcnt(0) only: global prefetch for tile kt+1
// stays in flight across the barrier (no vmcnt drain).
__global__ __launch_bounds__(512, 4) void k_fused(
    const float* __restrict__ x, const unsigned short* __restrict__ WinT,
    const float* __restrict__ b_in,
    const unsigned short* __restrict__ WblkT, const float* __restrict__ b_blk,
    unsigned short* __restrict__ h_out, unsigned short* __restrict__ z_out,
    float* __restrict__ mask_out,
    float* __restrict__ sumP, float* __restrict__ sumsqP)
{
    __shared__ unsigned short smem[16384];   // 32768 B
    unsigned short* stg = smem;              // [2][128][32] bf16
    unsigned short* h_s = smem;              // [128][128] bf16 (swizzled)

    const int tid = threadIdx.x;
    const int R0 = blockIdx.x * 128;
    const int wave = tid >> 6;   // 0..7
    const int wrow = wave >> 2;  // 0..1
    const int wcol = wave & 3;   // 0..3
    const int lane = tid & 63;
    const int lm = lane & 15, quad = lane >> 4;

    // staging role: thread covers row srow, 8 cols at sch*8 (per K-tile)
    const int srow = tid >> 2, sch = tid & 3;
    const int sgo = srow * 32 + ((sch ^ ((srow >> 1) & 3)) << 3);   // ushort units
    const float* xb = x + (size_t)(R0 + srow) * F_ + sch * 8;

    // GEMM1 A-frag LDS offsets (swizzled), per mi
    int aoff[4];
#pragma unroll
    for (int mi = 0; mi < 4; mi++) {
        const int ar = wrow * 64 + mi * 16 + lm;
        aoff[mi] = ar * 32 + ((quad ^ ((ar >> 1) & 3)) << 3);
    }
    // GEMM1 B-frag global pointers (WinT, L2-hot)
    const unsigned short* wr0 = WinT + (size_t)(wcol * 32 + lm) * F_ + quad * 8;
    const unsigned short* wr1 = wr0 + (size_t)16 * F_;

    f32x4 acc[4][2];
#pragma unroll
    for (int i = 0; i < 4; i++)
#pragma unroll
        for (int j = 0; j < 2; j++) acc[i][j] = (f32x4){0.f, 0.f, 0.f, 0.f};
    float msq = 0.f;

    // prologue: tile 0 -> regs
    float4 c0 = *(const float4*)(xb);
    float4 c1 = *(const float4*)(xb + 4);

    // ---- GEMM1: 8 K-steps of 32 ----
#pragma unroll
    for (int kt = 0; kt < 8; kt++) {
        float4 n0, n1;
        if (kt < 7) {                       // issue next-tile loads FIRST
            n0 = *(const float4*)(xb + (kt + 1) * 32);
            n1 = *(const float4*)(xb + (kt + 1) * 32 + 4);
        }
        short8 bC[2];                       // B-frags for this kt (L2)
        bC[0] = *(const short8*)(wr0 + kt * 32);
        bC[1] = *(const short8*)(wr1 + kt * 32);
        // stage tile kt (stalls only on c0/c1's own vmcnt)
        msq += c0.x * c0.x + c0.y * c0.y + c0.z * c0.z + c0.w * c0.w
             + c1.x * c1.x + c1.y * c1.y + c1.z * c1.z + c1.w * c1.w;
        *(short8*)(stg + (kt & 1) * 4096 + sgo) = pack_bf16x8(c0, c1);
        sync_lds();                          // tile kt visible; prefetch still flying
        short8 af[4];
#pragma unroll
        for (int mi = 0; mi < 4; mi++)
            af[mi] = *(const short8*)(stg + (kt & 1) * 4096 + aoff[mi]);
#pragma unroll
        for (int mi = 0; mi < 4; mi++)
#pragma unroll
            for (int ni = 0; ni < 2; ni++)
                acc[mi][ni] = __builtin_amdgcn_mfma_f32_16x16x32_bf16(af[mi], bC[ni], acc[mi][ni], 0, 0, 0);
        if (kt < 7) { c0 = n0; c1 = n1; }
    }

    // mask: reduce sumsq over the 4 col-chunks of each row (lanes t^1, t^2)
    msq += __shfl_xor(msq, 1, 64);
    msq += __shfl_xor(msq, 2, 64);
    if ((tid & 3) == 0) mask_out[R0 + srow] = (msq != 0.f) ? 1.f : 0.f;

    __syncthreads();   // all stg reads done before h_s overwrite

    // ---- epilogue 1: bias + relu -> h_s (swizzled) ----
    {
        float bcol[2];
#pragma unroll
        for (int ni = 0; ni < 2; ni++) bcol[ni] = b_in[wcol * 32 + ni * 16 + lm];
#pragma unroll
        for (int mi = 0; mi < 4; mi++)
#pragma unroll
            for (int r = 0; r < 4; r++) {
                const int rl = wrow * 64 + mi * 16 + quad * 4 + r;
#pragma unroll
                for (int ni = 0; ni < 2; ni++) {
                    const int col = wcol * 32 + ni * 16 + lm;
                    const float v = fmaxf(acc[mi][ni][r] + bcol[ni], 0.f);
                    h_s[rl * 128 + ((((col >> 3) ^ (rl & 7)) << 3) | (col & 7))] = f2bf(v);
                }
            }
    }
#pragma unroll
    for (int i = 0; i < 4; i++)
#pragma unroll
        for (int j = 0; j < 2; j++) acc[i][j] = (f32x4){0.f, 0.f, 0.f, 0.f};
    __syncthreads();   // h_s complete

    // ---- coalesced h_out stores from h_s (16B, fire-and-forget) ----
    {
        const int crow = tid >> 2, cb = tid & 3;
#pragma unroll
        for (int j = 0; j < 4; j++) {
            const int ch = cb * 4 + j;
            const short8 v = *(const short8*)(h_s + crow * 128 + ((ch ^ (crow & 7)) << 3));
            *(short8*)(h_out + (size_t)(R0 + crow) * HID_ + ch * 8) = v;
        }
    }

    // ---- GEMM2: A from h_s, B from WblkT (L2) ----
    {
        const unsigned short* wb0 = WblkT + (size_t)(wcol * 32 + lm) * HID_ + quad * 8;
        const unsigned short* wb1 = wb0 + (size_t)16 * HID_;
#pragma unroll
        for (int kt2 = 0; kt2 < 4; kt2++) {
            short8 wbf[2];
            wbf[0] = *(const short8*)(wb0 + kt2 * 32);
            wbf[1] = *(const short8*)(wb1 + kt2 * 32);
            short8 haf[4];
#pragma unroll
            for (int mi = 0; mi < 4; mi++) {
                const int hr = wrow * 64 + mi * 16 + lm;
                haf[mi] = *(const short8*)(h_s + hr * 128 + (((kt2 * 4 + quad) ^ (hr & 7)) << 3));
            }
#pragma unroll
            for (int mi = 0; mi < 4; mi++)
#pragma unroll
                for (int ni = 0; ni < 2; ni++)
                    acc[mi][ni] = __builtin_amdgcn_mfma_f32_16x16x32_bf16(haf[mi], wbf[ni], acc[mi][ni], 0, 0, 0);
        }
    }

    __syncthreads();   // all GEMM2 h_s reads done before z overwrite

    // ---- epilogue 2: bias, z -> h_s, BN partials via shfl ----
    {
        float bcol2[2];
#pragma unroll
        for (int ni = 0; ni < 2; ni++) bcol2[ni] = b_blk[wcol * 32 + ni * 16 + lm];
        float s_c[2] = {0.f, 0.f}, ss_c[2] = {0.f, 0.f};
#pragma unroll
        for (int mi = 0; mi < 4; mi++)
#pragma unroll
            for (int r = 0; r < 4; r++) {
                const int rl = wrow * 64 + mi * 16 + quad * 4 + r;
#pragma unroll
                for (int ni = 0; ni < 2; ni++) {
                    const int col = wcol * 32 + ni * 16 + lm;
                    const float zv = acc[mi][ni][r] + bcol2[ni];
                    s_c[ni] += zv;
                    ss_c[ni] += zv * zv;
                    h_s[rl * 128 + ((((col >> 3) ^ (rl & 7)) << 3) | (col & 7))] = f2bf(zv);
                }
            }
        // reduce over quad (rows) -> quad==0 lanes hold col sums for this wrow half
#pragma unroll
        for (int ni = 0; ni < 2; ni++) {
            s_c[ni]  += __shfl_xor(s_c[ni], 16, 64);
            s_c[ni]  += __shfl_xor(s_c[ni], 32, 64);
            ss_c[ni] += __shfl_xor(ss_c[ni], 16, 64);
            ss_c[ni] += __shfl_xor(ss_c[ni], 32, 64);
        }
        if (quad == 0) {
#pragma unroll
            for (int ni = 0; ni < 2; ni++) {
                const int col = wcol * 32 + ni * 16 + lm;
                sumP[((size_t)blockIdx.x * 2 + wrow) * 128 + col]   = s_c[ni];
                sumsqP[((size_t)blockIdx.x * 2 + wrow) * 128 + col] = ss_c[ni];
            }
        }
    }
    __syncthreads();   // z tile complete

    // ---- coalesced z_out stores ----
    {
        const int crow = tid >> 2, cb = tid & 3;
#pragma unroll
        for (int j = 0; j < 4; j++) {
            const int ch = cb * 4 + j;
            const short8 v = *(const short8*)(h_s + crow * 128 + ((ch ^ (crow & 7)) << 3));
            *(short8*)(z_out + (size_t)(R0 + crow) * HID_ + ch * 8) = v;
        }
    }
}

// ---------------- BN finalize (2048 partials now) ----------------------------
__global__ __launch_bounds__(256) void k_bnfin(
    const float* __restrict__ sumP, const float* __restrict__ sumsqP,
    const float* __restrict__ gamma, const float* __restrict__ beta,
    float* __restrict__ scale, float* __restrict__ shift)
{
    const int c = blockIdx.x;
    const int tid = threadIdx.x;
    float s = 0.f, ss = 0.f;
    for (int i = tid; i < 2048; i += 256) {
        s  += sumP[(size_t)i * 128 + c];
        ss += sumsqP[(size_t)i * 128 + c];
    }
#pragma unroll
    for (int off = 32; off; off >>= 1) {
        s  += __shfl_xor(s, off, 64);
        ss += __shfl_xor(ss, off, 64);
    }
    __shared__ float rs[4], rss[4];
    const int wid = tid >> 6, lane = tid & 63;
    if (lane == 0) { rs[wid] = s; rss[wid] = ss; }
    __syncthreads();
    if (tid == 0) {
        const float S  = rs[0] + rs[1] + rs[2] + rs[3];
        const float SS = rss[0] + rss[1] + rss[2] + rss[3];
        const float inv_m = 1.0f / (float)MB_;
        const float mu = S * inv_m;
        const float var = SS * inv_m - mu * mu;
        const float sc = gamma[c] * rsqrtf(var + 1e-5f);
        scale[c] = sc;
        shift[c] = beta[c] - mu * sc;
    }
}

// ---------------- logits + gumbel + per-(b,h) max ---------------------------
__global__ __launch_bounds__(256) void k_logits(
    const unsigned short* __restrict__ h_in, const unsigned short* __restrict__ z_in,
    const float* __restrict__ scale, const float* __restrict__ shift,
    const float* __restrict__ W_fc, const float* __restrict__ b_fc,
    const float* __restrict__ mask, const float* __restrict__ gumbel,
    float* __restrict__ t_out, unsigned int* __restrict__ Mmax)
{
    __shared__ float wfc_s[1024];
    __shared__ float sc_s[128], sh_s[128];
    const int tid = threadIdx.x;
    for (int i = tid; i < 1024; i += 256) wfc_s[i] = W_fc[i];
    if (tid < 128) { sc_s[tid] = scale[tid]; sh_s[tid] = shift[tid]; }
    __syncthreads();

    const size_t row0 = (size_t)blockIdx.x * 512 + tid;
    const size_t row1 = row0 + 256;
    float a0[8], a1[8];
#pragma unroll
    for (int j = 0; j < 8; j++) { a0[j] = 0.f; a1[j] = 0.f; }

    const uint4* hp0 = (const uint4*)(h_in + row0 * HID_);
    const uint4* zq0 = (const uint4*)(z_in + row0 * HID_);
    const uint4* hp1 = (const uint4*)(h_in + row1 * HID_);
    const uint4* zq1 = (const uint4*)(z_in + row1 * HID_);

#pragma unroll 2
    for (int kc = 0; kc < 16; kc++) {
        const uint4 h0 = hp0[kc], z0 = zq0[kc];
        const uint4 h1 = hp1[kc], z1 = zq1[kc];
        const unsigned int hs0[4] = {h0.x, h0.y, h0.z, h0.w};
        const unsigned int zs0[4] = {z0.x, z0.y, z0.z, z0.w};
        const unsigned int hs1[4] = {h1.x, h1.y, h1.z, h1.w};
        const unsigned int zs1[4] = {z1.x, z1.y, z1.z, z1.w};
#pragma unroll
        for (int p = 0; p < 4; p++) {
            const int k = kc * 8 + p * 2;
            const float sck0 = sc_s[k], shk0 = sh_s[k];
            const float sck1 = sc_s[k + 1], shk1 = sh_s[k + 1];
            const float4 wA = *(const float4*)&wfc_s[k * 8];
            const float4 wB = *(const float4*)&wfc_s[k * 8 + 4];
            const float4 wC = *(const float4*)&wfc_s[k * 8 + 8];
            const float4 wD = *(const float4*)&wfc_s[k * 8 + 12];
            {
                const float hf0 = bflo(hs0[p]), hf1 = bfhi(hs0[p]);
                const float zf0 = bflo(zs0[p]), zf1 = bfhi(zs0[p]);
                const float hb0 = fmaxf(zf0 * sck0 + shk0, 0.f) + hf0;
                const float hb1 = fmaxf(zf1 * sck1 + shk1, 0.f) + hf1;
                a0[0] += hb0 * wA.x + hb1 * wC.x;  a0[1] += hb0 * wA.y + hb1 * wC.y;
                a0[2] += hb0 * wA.z + hb1 * wC.z;  a0[3] += hb0 * wA.w + hb1 * wC.w;
                a0[4] += hb0 * wB.x + hb1 * wD.x;  a0[5] += hb0 * wB.y + hb1 * wD.y;
                a0[6] += hb0 * wB.z + hb1 * wD.z;  a0[7] += hb0 * wB.w + hb1 * wD.w;
            }
            {
                const float hf0 = bflo(hs1[p]), hf1 = bfhi(hs1[p]);
                const float zf0 = bflo(zs1[p]), zf1 = bfhi(zs1[p]);
                const float hb0 = fmaxf(zf0 * sck0 + shk0, 0.f) + hf0;
                const float hb1 = fmaxf(zf1 * sck1 + shk1, 0.f) + hf1;
                a1[0] += hb0 * wA.x + hb1 * wC.x;  a1[1] += hb0 * wA.y + hb1 * wC.y;
                a1[2] += hb0 * wA.z + hb1 * wC.z;  a1[3] += hb0 * wA.w + hb1 * wC.w;
                a1[4] += hb0 * wB.x + hb1 * wD.x;  a1[5] += hb0 * wB.y + hb1 * wD.y;
                a1[6] += hb0 * wB.z + hb1 * wD.z;  a1[7] += hb0 * wB.w + hb1 * wD.w;
            }
        }
    }

    float bf[8];
#pragma unroll
    for (int j = 0; j < 8; j++) bf[j] = b_fc[j];
    const float mk0 = mask[row0], mk1 = mask[row1];
    float g0[8], g1[8];
    *(float4*)&g0[0] = *(const float4*)(gumbel + row0 * 8);
    *(float4*)&g0[4] = *(const float4*)(gumbel + row0 * 8 + 4);
    *(float4*)&g1[0] = *(const float4*)(gumbel + row1 * 8);
    *(float4*)&g1[4] = *(const float4*)(gumbel + row1 * 8 + 4);
    float t0[8], t1[8];
#pragma unroll
    for (int j = 0; j < 8; j++) {
        t0[j] = (a0[j] + bf[j]) * mk0 + g0[j];
        t1[j] = (a1[j] + bf[j]) * mk1 + g1[j];
    }
    *(float4*)(t_out + row0 * 8)     = *(float4*)&t0[0];
    *(float4*)(t_out + row0 * 8 + 4) = *(float4*)&t0[4];
    *(float4*)(t_out + row1 * 8)     = *(float4*)&t1[0];
    *(float4*)(t_out + row1 * 8 + 4) = *(float4*)&t1[4];

    float tm[8];
#pragma unroll
    for (int j = 0; j < 8; j++) tm[j] = fmaxf(t0[j], t1[j]);
#pragma unroll
    for (int off = 32; off; off >>= 1)
#pragma unroll
        for (int j = 0; j < 8; j++) tm[j] = fmaxf(tm[j], __shfl_xor(tm[j], off, 64));
    if ((tid & 63) == 0) {
        const int bb = blockIdx.x >> 3;   // 512 rows per block, 4096 per b
#pragma unroll
        for (int j = 0; j < 8; j++) atomicMax(&Mmax[bb * 8 + j], fkey(tm[j]));
    }
}

// ---------------- pool: e=exp(t-M) on the fly, unnormalized wsum + Z --------
__global__ __launch_bounds__(256) void k_pool(
    const float* __restrict__ x, const float* __restrict__ t_in,
    const unsigned int* __restrict__ Mmax,
    float* __restrict__ pp, float* __restrict__ zp)
{
    __shared__ float ws_s[8][64];
    __shared__ float M_s[8];
    const int tid = threadIdx.x;
    const int oc = blockIdx.x;
    const int b  = blockIdx.y;
    if (tid < 8) {
        const unsigned int k = Mmax[b * 8 + tid];
        const unsigned int s = (k & 0x80000000u) ? (k & 0x7fffffffu) : ~k;
        M_s[tid] = __uint_as_float(s);
    }
    __syncthreads();
#pragma unroll
    for (int i = tid; i < 512; i += 256) {
        const int ol = i >> 3, hh = i & 7;
        const float tv = t_in[((size_t)b * O_ + oc * 64 + ol) * H_ + hh];
        ws_s[hh][ol] = __expf(tv - M_s[hh]);
    }
    __syncthreads();
    if (tid < 8) {
        float s = 0.f;
        for (int o = 0; o < 64; o++) s += ws_s[tid][o];
        zp[((size_t)oc * 32 + b) * 8 + tid] = s;
    }
    float acc[8];
#pragma unroll
    for (int hh = 0; hh < 8; hh++) acc[hh] = 0.f;
    const float* xp = x + ((size_t)b * O_ + oc * 64) * F_ + tid;
#pragma unroll 4
    for (int o = 0; o < 64; o++) {
        const float xv = xp[(size_t)o * F_];
#pragma unroll
        for (int hh = 0; hh < 8; hh++) acc[hh] += ws_s[hh][o] * xv;
    }
    float* outp = pp + ((size_t)oc * 32 + b) * 2048;
#pragma unroll
    for (int hh = 0; hh < 8; hh++) outp[hh * 256 + tid] = acc[hh];
}

// ---------------- reduce partials + divide by Z -----------------------------
__global__ __launch_bounds__(256) void k_reduce(
    const float* __restrict__ pp, const float* __restrict__ zp,
    float* __restrict__ out)
{
    const int blk = blockIdx.x;
    const int b = blk >> 3, hh = blk & 7;
    const int tid = threadIdx.x;
    __shared__ float invZ_s;
    if (tid < 64) {
        float z = zp[((size_t)tid * 32 + b) * 8 + hh];
#pragma unroll
        for (int off = 32; off; off >>= 1) z += __shfl_xor(z, off, 64);
        if (tid == 0) invZ_s = 1.f / z;
    }
    __syncthreads();
    float s = 0.f;
    const float* p0 = pp + (size_t)b * 2048 + hh * 256 + tid;
#pragma unroll 8
    for (int ocq = 0; ocq < 64; ocq++) s += p0[(size_t)ocq * 65536];
    out[(size_t)b * 2048 + hh * 256 + tid] = s * invZ_s;
}

extern "C" void kernel_launch(void* const* d_in, const int* in_sizes, int n_in,
                              void* d_out, int out_size, void* d_ws, size_t ws_size,
                              hipStream_t stream)
{
    const float* x      = (const float*)d_in[0];
    const float* gumbel = (const float*)d_in[1];
    const float* W_in   = (const float*)d_in[2];
    const float* b_in   = (const float*)d_in[3];
    const float* W_blk  = (const float*)d_in[4];
    const float* b_blk  = (const float*)d_in[5];
    const float* gamma  = (const float*)d_in[6];
    const float* beta   = (const float*)d_in[7];
    const float* W_fc   = (const float*)d_in[8];
    const float* b_fc   = (const float*)d_in[9];
    float* out = (float*)d_out;
    char* ws = (char*)d_ws;

    unsigned short* h_bf  = (unsigned short*)(ws + 0);            // 33554432
    float* pp     = (float*)(ws + 0);                              // 16777216 (alias)
    float* zp     = (float*)(ws + 16777216);                       // 65536    (alias)
    unsigned short* z_bf  = (unsigned short*)(ws + 33554432);      // 33554432
    float* mask   = (float*)(ws + 67108864);                       // 524288
    float* sumP   = (float*)(ws + 67633152);                       // 1048576 (2048x128)
    float* sumsqP = (float*)(ws + 68681728);                       // 1048576
    float* scale  = (float*)(ws + 69730304);                       // 512
    float* shift  = (float*)(ws + 69730816);                       // 512
    float* t_buf  = (float*)(ws + 69731328);                       // 4194304
    unsigned int* Mmax = (unsigned int*)(ws + 73925632);           // 1024
    unsigned short* WinT  = (unsigned short*)(ws + 73926656);      // 65536
    unsigned short* WblkT = (unsigned short*)(ws + 73992192);      // 32768

    k_prep<<<192, 256, 0, stream>>>(W_in, W_blk, WinT, WblkT, Mmax);
    k_fused<<<1024, 512, 0, stream>>>(x, WinT, b_in, WblkT, b_blk, h_bf, z_bf, mask, sumP, sumsqP);
    k_bnfin<<<128, 256, 0, stream>>>(sumP, sumsqP, gamma, beta, scale, shift);
    k_logits<<<256, 256, 0, stream>>>(h_bf, z_bf, scale, shift, W_fc, b_fc, mask, gumbel, t_buf, Mmax);
    k_pool<<<dim3(64, 32), 256, 0, stream>>>(x, t_buf, Mmax, pp, zp);
    k_reduce<<<256, 256, 0, stream>>>(pp, zp, out);
}